// Round 4
// baseline (317.697 us; speedup 1.0000x reference)
//
#include <hip/hip_runtime.h>
#include <cstdint>
#include <cstddef>

#define Bb 8
#define Ss 2048
#define Dd 512

typedef _Float16 half8 __attribute__((ext_vector_type(8)));
typedef _Float16 half4_ __attribute__((ext_vector_type(4)));
typedef float f32x4 __attribute__((ext_vector_type(4)));

static __device__ __forceinline__ void gload_lds16(const void* g, void* l) {
  __builtin_amdgcn_global_load_lds((const __attribute__((address_space(1))) void*)g,
                                   (__attribute__((address_space(3))) void*)l,
                                   16, 0, 0);
}

// ---------------- K0: fused prep (unchanged, verified) ----------------
__global__ void k0_prep(const float* __restrict__ enc, const float* __restrict__ dec,
                        _Float16* __restrict__ enc16, _Float16* __restrict__ encT,
                        _Float16* __restrict__ dec16) {
  __shared__ _Float16 tb[8][64][8];  // [key>>3][d][key&7], 8 KB
  int bid = blockIdx.x;
  int b = bid & 7, kt = (bid >> 3) & 31, dt = bid >> 8;
  int key0 = kt * 64, d0 = dt * 64;
  int t = threadIdx.x;

  {
    size_t off = (size_t)bid * 4096 + (size_t)t * 16;
    const float4* p = (const float4*)(dec + off);
    float4 a0 = p[0], a1 = p[1], a2 = p[2], a3 = p[3];
    half8 h0, h1;
    h0[0] = (_Float16)a0.x; h0[1] = (_Float16)a0.y; h0[2] = (_Float16)a0.z; h0[3] = (_Float16)a0.w;
    h0[4] = (_Float16)a1.x; h0[5] = (_Float16)a1.y; h0[6] = (_Float16)a1.z; h0[7] = (_Float16)a1.w;
    h1[0] = (_Float16)a2.x; h1[1] = (_Float16)a2.y; h1[2] = (_Float16)a2.z; h1[3] = (_Float16)a2.w;
    h1[4] = (_Float16)a3.x; h1[5] = (_Float16)a3.y; h1[6] = (_Float16)a3.z; h1[7] = (_Float16)a3.w;
    *(half8*)(dec16 + off) = h0;
    *(half8*)(dec16 + off + 8) = h1;
  }

  const float* src = enc + ((size_t)b * Ss + key0) * Dd + d0;
  _Float16* d16 = enc16 + ((size_t)b * Ss + key0) * Dd + d0;
#pragma unroll
  for (int p = 0; p < 4; ++p) {
    int row = p * 16 + (t >> 4);
    int c = (t & 15) * 4;
    float4 a = *(const float4*)(src + (size_t)row * Dd + c);
    half4_ h;
    h[0] = (_Float16)a.x; h[1] = (_Float16)a.y; h[2] = (_Float16)a.z; h[3] = (_Float16)a.w;
    *(half4_*)(d16 + (size_t)row * Dd + c) = h;
    int K = row >> 3, k = row & 7;
#pragma unroll
    for (int i = 0; i < 4; ++i) tb[K][c + i][k] = h[i];
  }
  __syncthreads();

  _Float16* oT = encT + ((size_t)b * Dd + d0) * Ss + key0;
#pragma unroll
  for (int q = 0; q < 2; ++q) {
    int d = q * 32 + (t >> 3);
    int k8 = (t & 7) * 8;
    half8 v = *(const half8*)&tb[k8 >> 3][d][0];
    *(half8*)(oT + (size_t)d * Ss + k8) = v;
  }
}

// ---------------- KF: fused flash attention (replaces k1 + k3) ----------------
// 256 blocks (b = bid&7 -> batch pinned per XCD), 512 threads (8 waves).
// Per block: 64 q-rows x 2048 keys, KB=32 per step, 64 steps.
//   Q:  registers (16 x half8 per lane = exact A-fragments, no LDS traffic)
//   K tile (E, 32x512): LDS, double-buffered, global_load_lds, chunk-XOR swizzle,
//        counted vmcnt: steady state waits vmcnt(8) pre-QK^T / vmcnt(4) pre-PV, never 0.
//   V fragments: register-direct inline-asm global_load_dwordx4 from encT (L2-resident),
//        issued at tile top, consumed after softmax (T14 async split).
//   Online softmax: f32 m/l per row in LDS; flagged (defer) O-rescale.
#define WAITVM(N) do { asm volatile("s_waitcnt vmcnt(" #N ")" ::: "memory"); __builtin_amdgcn_sched_barrier(0); } while (0)
#define LGKM0 asm volatile("s_waitcnt lgkmcnt(0)" ::: "memory")
#define BARR() __builtin_amdgcn_s_barrier()

__launch_bounds__(512, 2)
__global__ void kf_attn(const _Float16* __restrict__ Qm, const _Float16* __restrict__ Em,
                        const _Float16* __restrict__ Vt, float* __restrict__ C) {
  extern __shared__ _Float16 smem[];           // E0 | E1 | pS | f32 state ; 72 KB
  _Float16* pS = smem + 32768;                 // [64][32] f16 (chunk-XOR by row&3)
  float* fb = (float*)(smem + 34816);
  float* wMax = fb;                            // [2][64]
  float* wSum = fb + 128;                      // [2][64]
  float* fct  = fb + 256;                      // [64] rescale factor / final rinv
  float* negm = fb + 320;                      // [64] running max
  float* mst  = fb + 384;                      // [64]
  float* lst  = fb + 448;                      // [64]
  int*   flg  = (int*)(fb + 512);

  int bid = blockIdx.x;
  int b = bid & 7, qt = bid >> 3;              // batch-per-XCD swizzle
  int q0 = qt * 64;
  int tid = threadIdx.x;
  int w = tid >> 6, L = tid & 63;
  int g = L >> 4, lm = L & 15;
  int wm4 = w >> 1, wn2 = w & 1;               // QK^T wave grid: 4m x 2n over 64x32
  int k7 = lm & 7;

  // ---- Q fragments: rows wm4*16+lm, full K=512 (A-frag layout: k = g*8 + j) ----
  half8 qf[16];
  {
    const _Float16* qp = Qm + ((size_t)(b * Ss + q0 + wm4 * 16 + lm)) * Dd + g * 8;
#pragma unroll
    for (int ks = 0; ks < 16; ++ks) qf[ks] = *(const half8*)(qp + ks * 32);
  }

  if (tid < 64) { mst[tid] = -1e30f; lst[tid] = 0.f; }

  // ---- E staging: 4 gload_lds16 per thread per tile; lane-linear LDS dest,
  //      pre-swizzled global source (chunk c stored from global chunk c ^ (key&7)) ----
  const _Float16* eg[4]; int els[4];
#pragma unroll
  for (int r = 0; r < 4; ++r) {
    int key = r * 8 + w;                       // 0..31
    els[r] = key * 512 + L * 8;
    eg[r] = Em + ((size_t)(b * Ss) + key) * Dd + ((L ^ (key & 7)) * 8);
  }
  // ---- V direct-load byte addresses (per wave 64-col d-slice) ----
  uint64_t vb[4];
#pragma unroll
  for (int nt = 0; nt < 4; ++nt)
    vb[nt] = (uint64_t)(uintptr_t)(Vt + ((size_t)(b * Dd + w * 64 + nt * 16 + lm)) * Ss + g * 8);

  f32x4 acc[4][4];
#pragma unroll
  for (int mt = 0; mt < 4; ++mt)
#pragma unroll
    for (int nt = 0; nt < 4; ++nt) acc[mt][nt] = (f32x4){0.f, 0.f, 0.f, 0.f};

  // ---- prologue: stage E(0) into buf0 ----
#pragma unroll
  for (int r = 0; r < 4; ++r) gload_lds16(eg[r], smem + els[r]);
  LGKM0;
  BARR();   // state init visible; E(0) still in flight (counted below)

#pragma unroll 1
  for (int t = 0; t < 64; ++t) {
    bool pre = t < 63;
    const _Float16* eC = smem + ((t & 1) << 14);
    _Float16* eN = smem + (((t + 1) & 1) << 14);

    // step 1: issue V-fragment loads for tile t (asm: issue point pinned, no auto-wait)
    f32x4 bfr[4];
#pragma unroll
    for (int nt = 0; nt < 4; ++nt) {
      uint64_t a = vb[nt] + (uint64_t)t * 64;
      asm volatile("global_load_dwordx4 %0, %1, off" : "=v"(bfr[nt]) : "v"(a));
    }
    // step 2: stage E(t+1) into the other buffer
    if (pre) {
#pragma unroll
      for (int r = 0; r < 4; ++r) gload_lds16(eg[r] + (size_t)(t + 1) * 16384, eN + els[r]);
    }
    // step 3: ensure E(t) landed (oldest 4 of [E(t),bf(t),E(t+1)]), then block-wide sync
    if (pre) { WAITVM(8); } else { WAITVM(4); }
    BARR();

    // ---- QK^T: S[64x32] piece 16x16 per wave; 2 accumulator chains for ILP ----
    f32x4 s0 = (f32x4){0.f, 0.f, 0.f, 0.f}, s1 = (f32x4){0.f, 0.f, 0.f, 0.f};
    const _Float16* eRow = eC + (wn2 * 16 + lm) * 512;
    __builtin_amdgcn_s_setprio(1);
#pragma unroll
    for (int ks = 0; ks < 16; ks += 2) {
      half8 b0 = *(const half8*)(eRow + (((ks * 4 + g) ^ k7) << 3));
      half8 b1 = *(const half8*)(eRow + ((((ks + 1) * 4 + g) ^ k7) << 3));
      s0 = __builtin_amdgcn_mfma_f32_16x16x32_f16(qf[ks], b0, s0, 0, 0, 0);
      s1 = __builtin_amdgcn_mfma_f32_16x16x32_f16(qf[ks + 1], b1, s1, 0, 0, 0);
    }
    __builtin_amdgcn_s_setprio(0);
    f32x4 sa = s0 + s1;   // S[wm4*16+g*4+r][wn2*16+lm]

    // ---- softmax: per-row max (16 cols in-wave, cross-wn2 via LDS) ----
#pragma unroll
    for (int r = 0; r < 4; ++r) {
      float m = sa[r];
      m = fmaxf(m, __shfl_xor(m, 1));
      m = fmaxf(m, __shfl_xor(m, 2));
      m = fmaxf(m, __shfl_xor(m, 4));
      m = fmaxf(m, __shfl_xor(m, 8));
      if (lm == 0) wMax[wn2 * 64 + wm4 * 16 + g * 4 + r] = m;
    }
    LGKM0; BARR();   // B1

    if (tid < 64) {  // wave 0 = row-state updater
      float tmax = fmaxf(wMax[tid], wMax[64 + tid]);
      float mo = mst[tid];
      float mn = fmaxf(mo, tmax);
      fct[tid] = __expf(mo - mn);
      negm[tid] = mn;
      mst[tid] = mn;
      unsigned long long bal = __ballot(tmax > mo);
      if (tid == 0) *flg = (bal != 0ULL) ? 1 : 0;
    }
    LGKM0; BARR();   // B2

    // ---- P = exp(S - m), store f16 to pS (chunk XOR row&3), partial row sums ----
    int cc = wn2 * 2 + (lm >> 3);
#pragma unroll
    for (int r = 0; r < 4; ++r) {
      int R = wm4 * 16 + g * 4 + r;
      float p = __expf(sa[r] - negm[R]);
      pS[R * 32 + (((cc ^ r) << 3) | k7)] = (_Float16)p;
      float s = p;
      s += __shfl_xor(s, 1); s += __shfl_xor(s, 2);
      s += __shfl_xor(s, 4); s += __shfl_xor(s, 8);
      if (lm == 0) wSum[wn2 * 64 + R] = s;
    }
    LGKM0; BARR();   // B3

    if (tid < 64) lst[tid] = lst[tid] * fct[tid] + wSum[tid] + wSum[64 + tid];

    // ---- deferred O-rescale: only when some row's max grew this tile ----
    if (*flg) {
#pragma unroll
      for (int mt = 0; mt < 4; ++mt)
#pragma unroll
        for (int rr = 0; rr < 4; ++rr) {
          float f = fct[mt * 16 + g * 4 + rr];
#pragma unroll
          for (int nt = 0; nt < 4; ++nt) acc[mt][nt][rr] *= f;
        }
    }

    // step 6: V fragments landed (oldest 4 of [bf(t), E(t+1)]); E(t+1) stays in flight
    if (pre) { WAITVM(4); } else { WAITVM(0); }

    // ---- PV: O[64 x 64-col-slice] per wave; A = pS, B = V regs ----
    half8 af[4];
#pragma unroll
    for (int mt = 0; mt < 4; ++mt)
      af[mt] = *(const half8*)(pS + (mt * 16 + lm) * 32 + ((g ^ (lm & 3)) << 3));
    __builtin_amdgcn_s_setprio(1);
#pragma unroll
    for (int mt = 0; mt < 4; ++mt)
#pragma unroll
      for (int nt = 0; nt < 4; ++nt)
        acc[mt][nt] = __builtin_amdgcn_mfma_f32_16x16x32_f16(af[mt], *(half8*)&bfr[nt],
                                                             acc[mt][nt], 0, 0, 0);
    __builtin_amdgcn_s_setprio(0);
    // no trailing barrier needed: next tile's step-3 barrier + B1/B2 separate all reuses
  }

  // ---- epilogue: O / l ----
  LGKM0; BARR();
  if (tid < 64) fct[tid] = 1.0f / lst[tid];
  LGKM0; BARR();
#pragma unroll
  for (int mt = 0; mt < 4; ++mt)
#pragma unroll
    for (int rr = 0; rr < 4; ++rr) {
      int R = mt * 16 + g * 4 + rr;
      float ri = fct[R];
      float* Crow = C + ((size_t)(b * Ss + q0 + R)) * Dd + w * 64 + lm;
#pragma unroll
      for (int nt = 0; nt < 4; ++nt) Crow[nt * 16] = acc[mt][nt][rr] * ri;
    }
}

extern "C" void kernel_launch(void* const* d_in, const int* in_sizes, int n_in,
                              void* d_out, int out_size, void* d_ws, size_t ws_size,
                              hipStream_t stream) {
  const float* enc = (const float*)d_in[0];
  const float* dec = (const float*)d_in[1];
  float* out = (float*)d_out;

  const size_t nElem = (size_t)Bb * Ss * Dd;  // 8388608

  _Float16* dec16 = (_Float16*)d_ws;
  _Float16* enc16 = dec16 + nElem;
  _Float16* encT = enc16 + nElem;

  size_t need = nElem * 2 * 3;
  if (ws_size < need) return;

  static int g_attr = 0;
  if (!g_attr) {
    (void)hipFuncSetAttribute(reinterpret_cast<const void*>(&kf_attn),
                              hipFuncAttributeMaxDynamicSharedMemorySize, 73728);
    g_attr = 1;
  }

  k0_prep<<<2048, 256, 0, stream>>>(enc, dec, enc16, encT, dec16);
  kf_attn<<<256, 512, 73728, stream>>>(dec16, enc16, encT, out);
}

// Round 5
// 203.977 us; speedup vs baseline: 1.5575x; 1.5575x over previous
//
#include <hip/hip_runtime.h>
#include <cstdint>
#include <cstddef>

#define Bb 8
#define Ss 2048
#define Dd 512

typedef _Float16 half8 __attribute__((ext_vector_type(8)));
typedef _Float16 half4_ __attribute__((ext_vector_type(4)));
typedef _Float16 half2_t __attribute__((ext_vector_type(2)));
typedef float f32x4 __attribute__((ext_vector_type(4)));

static __device__ __forceinline__ void gload_lds16(const void* g, void* l) {
  __builtin_amdgcn_global_load_lds((const __attribute__((address_space(1))) void*)g,
                                   (__attribute__((address_space(3))) void*)l,
                                   16, 0, 0);
}

// ---------------- K0: fused prep (round-0 verified, unchanged) ----------------
__global__ void k0_prep(const float* __restrict__ enc, const float* __restrict__ dec,
                        _Float16* __restrict__ enc16, _Float16* __restrict__ encT,
                        _Float16* __restrict__ dec16) {
  __shared__ _Float16 tb[8][64][8];  // [key>>3][d][key&7], 8 KB
  int bid = blockIdx.x;
  int b = bid & 7, kt = (bid >> 3) & 31, dt = bid >> 8;
  int key0 = kt * 64, d0 = dt * 64;
  int t = threadIdx.x;

  {
    size_t off = (size_t)bid * 4096 + (size_t)t * 16;
    const float4* p = (const float4*)(dec + off);
    float4 a0 = p[0], a1 = p[1], a2 = p[2], a3 = p[3];
    half8 h0, h1;
    h0[0] = (_Float16)a0.x; h0[1] = (_Float16)a0.y; h0[2] = (_Float16)a0.z; h0[3] = (_Float16)a0.w;
    h0[4] = (_Float16)a1.x; h0[5] = (_Float16)a1.y; h0[6] = (_Float16)a1.z; h0[7] = (_Float16)a1.w;
    h1[0] = (_Float16)a2.x; h1[1] = (_Float16)a2.y; h1[2] = (_Float16)a2.z; h1[3] = (_Float16)a2.w;
    h1[4] = (_Float16)a3.x; h1[5] = (_Float16)a3.y; h1[6] = (_Float16)a3.z; h1[7] = (_Float16)a3.w;
    *(half8*)(dec16 + off) = h0;
    *(half8*)(dec16 + off + 8) = h1;
  }

  const float* src = enc + ((size_t)b * Ss + key0) * Dd + d0;
  _Float16* d16 = enc16 + ((size_t)b * Ss + key0) * Dd + d0;
#pragma unroll
  for (int p = 0; p < 4; ++p) {
    int row = p * 16 + (t >> 4);
    int c = (t & 15) * 4;
    float4 a = *(const float4*)(src + (size_t)row * Dd + c);
    half4_ h;
    h[0] = (_Float16)a.x; h[1] = (_Float16)a.y; h[2] = (_Float16)a.z; h[3] = (_Float16)a.w;
    *(half4_*)(d16 + (size_t)row * Dd + c) = h;
    int K = row >> 3, k = row & 7;
#pragma unroll
    for (int i = 0; i < 4; ++i) tb[K][c + i][k] = h[i];
  }
  __syncthreads();

  _Float16* oT = encT + ((size_t)b * Dd + d0) * Ss + key0;
#pragma unroll
  for (int q = 0; q < 2; ++q) {
    int d = q * 32 + (t >> 3);
    int k8 = (t & 7) * 8;
    half8 v = *(const half8*)&tb[k8 >> 3][d][0];
    *(half8*)(oT + (size_t)d * Ss + k8) = v;
  }
}

// ---------------- K1: round-0 verified 2-phase 128x128 (the 53 us version) ----------
__launch_bounds__(256, 2)
__global__ void k1_qk(const _Float16* __restrict__ A, const _Float16* __restrict__ Bm,
                      _Float16* __restrict__ S, half2_t* __restrict__ pms) {
  __shared__ __align__(16) _Float16 lA[128 * 64];
  __shared__ __align__(16) _Float16 lB[128 * 64];
  int bid = blockIdx.x;
  int b = bid & 7;
  int t = bid >> 3;
  int tm = t & 15, tn = t >> 4;
  int tid = threadIdx.x;
  int w = tid >> 6, L = tid & 63;
  int wm = w & 1, wn = w >> 1;

  const _Float16* Ag = A + ((size_t)b * Ss + (size_t)tm * 128) * Dd;
  const _Float16* Bg = Bm + ((size_t)b * Ss + (size_t)tn * 128) * Dd;

  int rowS[4], colS[4], ldsOff[4];
#pragma unroll
  for (int i = 0; i < 4; ++i) {
    int se = (w * 4 + i) * 512 + L * 8;
    int row = se >> 6;
    int blk = (se >> 3) & 7;
    rowS[i] = row;
    colS[i] = (blk ^ (row & 7)) << 3;
    ldsOff[i] = se;
  }

  f32x4 acc[4][4];
#pragma unroll
  for (int mt = 0; mt < 4; ++mt)
#pragma unroll
    for (int nt = 0; nt < 4; ++nt) acc[mt][nt] = (f32x4){0.f, 0.f, 0.f, 0.f};

  int g = L >> 4, lm = L & 15;

  for (int k0 = 0; k0 < Dd; k0 += 64) {
    __syncthreads();
#pragma unroll
    for (int i = 0; i < 4; ++i) {
      gload_lds16(Ag + (size_t)rowS[i] * Dd + k0 + colS[i], lA + ldsOff[i]);
      gload_lds16(Bg + (size_t)rowS[i] * Dd + k0 + colS[i], lB + ldsOff[i]);
    }
    __syncthreads();
#pragma unroll
    for (int ds = 0; ds < 64; ds += 32) {
      half8 af[4], bf[4];
#pragma unroll
      for (int mt = 0; mt < 4; ++mt) {
        int row = wm * 64 + mt * 16 + lm;
        int blk = ((ds >> 3) + g) ^ (row & 7);
        af[mt] = *(const half8*)(lA + row * 64 + blk * 8);
      }
#pragma unroll
      for (int nt = 0; nt < 4; ++nt) {
        int row = wn * 64 + nt * 16 + lm;
        int blk = ((ds >> 3) + g) ^ (row & 7);
        bf[nt] = *(const half8*)(lB + row * 64 + blk * 8);
      }
#pragma unroll
      for (int mt = 0; mt < 4; ++mt)
#pragma unroll
        for (int nt = 0; nt < 4; ++nt)
          acc[mt][nt] = __builtin_amdgcn_mfma_f32_16x16x32_f16(af[mt], bf[nt], acc[mt][nt], 0, 0, 0);
    }
  }

  size_t rowbase = (size_t)b * Ss;
#pragma unroll
  for (int mt = 0; mt < 4; ++mt) {
#pragma unroll
    for (int r = 0; r < 4; ++r) {
      int row_g = tm * 128 + wm * 64 + mt * 16 + g * 4 + r;
      _Float16* Srow = S + (rowbase + row_g) * Ss + (size_t)tn * 128 + wn * 64 + lm;
      float rm = -1e30f;
#pragma unroll
      for (int nt = 0; nt < 4; ++nt) rm = fmaxf(rm, acc[mt][nt][r]);
      rm = fmaxf(rm, __shfl_xor(rm, 1));
      rm = fmaxf(rm, __shfl_xor(rm, 2));
      rm = fmaxf(rm, __shfl_xor(rm, 4));
      rm = fmaxf(rm, __shfl_xor(rm, 8));
      _Float16 mh = (_Float16)rm;   // f16-rounded chunk max; SAME value re-derived in k3 prologue
      float mf = (float)mh;
      float sum = 0.f;
#pragma unroll
      for (int nt = 0; nt < 4; ++nt) {
        float e = __expf(acc[mt][nt][r] - mf);
        Srow[nt * 16] = (_Float16)e;
        sum += e;
      }
      sum += __shfl_xor(sum, 1);
      sum += __shfl_xor(sum, 2);
      sum += __shfl_xor(sum, 4);
      sum += __shfl_xor(sum, 8);
      if (lm == 0) {
        half2_t st; st.x = mh; st.y = (_Float16)sum;
        pms[(rowbase + row_g) * 32 + tn * 2 + wn] = st;
      }
    }
  }
}

// ---------------- K3 v2: C = (e .* factor) @ V — 128x128 tiles, 4x4 acc ----------------
// Upgrade from 128x64: S-panel re-read redundancy 8 -> 4 (each S byte read by 4 tn-blocks),
// per-MFMA LDS reads 0.75 -> 0.5 b128 (af 4 + bf 4 feed 32 MFMAs per ds-half).
// LDS 48 KB (lA 16K + lB 16K + fctL 16K) -> 3 blocks/CU, 12 waves/CU.
// tn = t&3 (fastest) so the 4 blocks sharing an S panel are grid-adjacent -> same-XCD L2 reuse.
__launch_bounds__(256, 3)
__global__ void k3_pv(const _Float16* __restrict__ P, const _Float16* __restrict__ Vt,
                      const half2_t* __restrict__ pms, float* __restrict__ C) {
  __shared__ __align__(16) _Float16 lA[128 * 64];
  __shared__ __align__(16) _Float16 lB[128 * 64];
  __shared__ float fctL[32 * 128];  // [chunk][row] 16 KB
  int bid = blockIdx.x;
  int b = bid & 7;
  int t = bid >> 3;                 // 0..63
  int tn = t & 3, tm = t >> 2;      // 4 n-tiles (128 cols), 16 m-tiles (128 rows)
  int tid = threadIdx.x;
  int w = tid >> 6, L = tid & 63;
  int wm = w & 1, wn = w >> 1;      // 2x2 wave grid; per-wave output 64x64

  // ---- prologue: per-row softmax factors for this block's 128 rows ----
  if (tid < 128) {
    const half2_t* pr = pms + ((size_t)b * Ss + (size_t)tm * 128 + tid) * 32;
    float mc[32], sc[32];
#pragma unroll
    for (int c = 0; c < 32; ++c) { half2_t v = pr[c]; mc[c] = (float)v.x; sc[c] = (float)v.y; }
    float m = mc[0];
#pragma unroll
    for (int c = 1; c < 32; ++c) m = fmaxf(m, mc[c]);
    float tot = 0.f;
    float ef[32];
#pragma unroll
    for (int c = 0; c < 32; ++c) { ef[c] = __expf(mc[c] - m); tot += sc[c] * ef[c]; }
    float rinv = 1.0f / tot;
#pragma unroll
    for (int c = 0; c < 32; ++c) fctL[c * 128 + tid] = ef[c] * rinv;
  }

  const _Float16* Ag = P + ((size_t)b * Ss + (size_t)tm * 128) * Ss;   // pitch 2048
  const _Float16* Bg = Vt + ((size_t)b * Dd + (size_t)tn * 128) * Ss;  // pitch 2048

  // staging: lA and lB each 16 KB = 4 rounds x 256 thr x 16B, same pattern
  int rowS[4], colS[4], offS[4];
#pragma unroll
  for (int i = 0; i < 4; ++i) {
    int se = (w * 4 + i) * 512 + L * 8;
    int row = se >> 6;                // 0..127
    int blk = (se >> 3) & 7;
    rowS[i] = row;
    colS[i] = (blk ^ (row & 7)) << 3;
    offS[i] = se;
  }

  f32x4 acc[4][4];
#pragma unroll
  for (int mt = 0; mt < 4; ++mt)
#pragma unroll
    for (int nt = 0; nt < 4; ++nt) acc[mt][nt] = (f32x4){0.f, 0.f, 0.f, 0.f};

  int g = L >> 4, lm = L & 15;

  for (int k0 = 0; k0 < Ss; k0 += 64) {
    __syncthreads();
#pragma unroll
    for (int i = 0; i < 4; ++i) {
      gload_lds16(Ag + (size_t)rowS[i] * Ss + k0 + colS[i], lA + offS[i]);
      gload_lds16(Bg + (size_t)rowS[i] * Ss + k0 + colS[i], lB + offS[i]);
    }
    __syncthreads();
    _Float16 fh[4];
#pragma unroll
    for (int mt = 0; mt < 4; ++mt)
      fh[mt] = (_Float16)fctL[(k0 >> 6) * 128 + wm * 64 + mt * 16 + lm];
#pragma unroll
    for (int ds = 0; ds < 64; ds += 32) {
      half8 af[4], bf[4];
#pragma unroll
      for (int mt = 0; mt < 4; ++mt) {
        int row = wm * 64 + mt * 16 + lm;
        int blk = ((ds >> 3) + g) ^ (row & 7);
        af[mt] = *(const half8*)(lA + row * 64 + blk * 8);
#pragma unroll
        for (int j = 0; j < 8; ++j) af[mt][j] *= fh[mt];
      }
#pragma unroll
      for (int nt = 0; nt < 4; ++nt) {
        int row = wn * 64 + nt * 16 + lm;
        int blk = ((ds >> 3) + g) ^ (row & 7);
        bf[nt] = *(const half8*)(lB + row * 64 + blk * 8);
      }
#pragma unroll
      for (int mt = 0; mt < 4; ++mt)
#pragma unroll
        for (int nt = 0; nt < 4; ++nt)
          acc[mt][nt] = __builtin_amdgcn_mfma_f32_16x16x32_f16(af[mt], bf[nt], acc[mt][nt], 0, 0, 0);
    }
  }

  // epilogue: fp32 store, 64B contiguous runs per (mt, r, nt)
#pragma unroll
  for (int mt = 0; mt < 4; ++mt) {
#pragma unroll
    for (int r = 0; r < 4; ++r) {
      int row_g = tm * 128 + wm * 64 + mt * 16 + g * 4 + r;
      float* Crow = C + ((size_t)b * Ss + row_g) * Dd + (size_t)tn * 128 + wn * 64 + lm;
#pragma unroll
      for (int nt = 0; nt < 4; ++nt) Crow[nt * 16] = acc[mt][nt][r];
    }
  }
}

extern "C" void kernel_launch(void* const* d_in, const int* in_sizes, int n_in,
                              void* d_out, int out_size, void* d_ws, size_t ws_size,
                              hipStream_t stream) {
  const float* enc = (const float*)d_in[0];
  const float* dec = (const float*)d_in[1];
  float* out = (float*)d_out;

  const size_t nElem = (size_t)Bb * Ss * Dd;  // 8388608
  const size_t nS = (size_t)Bb * Ss * Ss;     // 33554432

  _Float16* dec16 = (_Float16*)d_ws;
  _Float16* enc16 = dec16 + nElem;
  _Float16* encT = enc16 + nElem;
  _Float16* Sp = encT + nElem;
  half2_t* pms = (half2_t*)(Sp + nS);

  size_t need = nElem * 2 * 3 + nS * 2 + (size_t)Bb * Ss * 32 * 4;
  if (ws_size < need) return;

  k0_prep<<<2048, 256, 0, stream>>>(enc, dec, enc16, encT, dec16);
  k1_qk<<<2048, 256, 0, stream>>>(dec16, enc16, Sp, pms);
  k3_pv<<<512, 256, 0, stream>>>(Sp, encT, pms, out);
}

// Round 6
// 202.184 us; speedup vs baseline: 1.5713x; 1.0089x over previous
//
#include <hip/hip_runtime.h>
#include <cstdint>
#include <cstddef>

#define Bb 8
#define Ss 2048
#define Dd 512

typedef _Float16 half8 __attribute__((ext_vector_type(8)));
typedef _Float16 half4_ __attribute__((ext_vector_type(4)));
typedef _Float16 half2_t __attribute__((ext_vector_type(2)));
typedef float f32x4 __attribute__((ext_vector_type(4)));

static __device__ __forceinline__ void gload_lds16(const void* g, void* l) {
  __builtin_amdgcn_global_load_lds((const __attribute__((address_space(1))) void*)g,
                                   (__attribute__((address_space(3))) void*)l,
                                   16, 0, 0);
}

// ---------------- K0: fused prep (round-0 verified, unchanged) ----------------
__global__ void k0_prep(const float* __restrict__ enc, const float* __restrict__ dec,
                        _Float16* __restrict__ enc16, _Float16* __restrict__ encT,
                        _Float16* __restrict__ dec16) {
  __shared__ _Float16 tb[8][64][8];  // [key>>3][d][key&7], 8 KB
  int bid = blockIdx.x;
  int b = bid & 7, kt = (bid >> 3) & 31, dt = bid >> 8;
  int key0 = kt * 64, d0 = dt * 64;
  int t = threadIdx.x;

  {
    size_t off = (size_t)bid * 4096 + (size_t)t * 16;
    const float4* p = (const float4*)(dec + off);
    float4 a0 = p[0], a1 = p[1], a2 = p[2], a3 = p[3];
    half8 h0, h1;
    h0[0] = (_Float16)a0.x; h0[1] = (_Float16)a0.y; h0[2] = (_Float16)a0.z; h0[3] = (_Float16)a0.w;
    h0[4] = (_Float16)a1.x; h0[5] = (_Float16)a1.y; h0[6] = (_Float16)a1.z; h0[7] = (_Float16)a1.w;
    h1[0] = (_Float16)a2.x; h1[1] = (_Float16)a2.y; h1[2] = (_Float16)a2.z; h1[3] = (_Float16)a2.w;
    h1[4] = (_Float16)a3.x; h1[5] = (_Float16)a3.y; h1[6] = (_Float16)a3.z; h1[7] = (_Float16)a3.w;
    *(half8*)(dec16 + off) = h0;
    *(half8*)(dec16 + off + 8) = h1;
  }

  const float* src = enc + ((size_t)b * Ss + key0) * Dd + d0;
  _Float16* d16 = enc16 + ((size_t)b * Ss + key0) * Dd + d0;
#pragma unroll
  for (int p = 0; p < 4; ++p) {
    int row = p * 16 + (t >> 4);
    int c = (t & 15) * 4;
    float4 a = *(const float4*)(src + (size_t)row * Dd + c);
    half4_ h;
    h[0] = (_Float16)a.x; h[1] = (_Float16)a.y; h[2] = (_Float16)a.z; h[3] = (_Float16)a.w;
    *(half4_*)(d16 + (size_t)row * Dd + c) = h;
    int K = row >> 3, k = row & 7;
#pragma unroll
    for (int i = 0; i < 4; ++i) tb[K][c + i][k] = h[i];
  }
  __syncthreads();

  _Float16* oT = encT + ((size_t)b * Dd + d0) * Ss + key0;
#pragma unroll
  for (int q = 0; q < 2; ++q) {
    int d = q * 32 + (t >> 3);
    int k8 = (t & 7) * 8;
    half8 v = *(const half8*)&tb[k8 >> 3][d][0];
    *(half8*)(oT + (size_t)d * Ss + k8) = v;
  }
}

// ---------------- K1 v5: 128x256 block tile, wave-tile 64x128, 2-phase loop ----------
// Same verified 2-barrier sync structure and XOR-swizzle as round 0; only the tile
// geometry changes. Per K=32 half-step a wave reads 4 af + 8 bf (12 b128) feeding
// 32 MFMAs, vs 8 reads / 16 MFMAs before -> staged+read LDS bytes per FLOP = 0.75x.
// acc[4][8] = 128 AGPR + ~70 VGPR < 256 @ 2 waves/SIMD; LDS 48 KB -> 2 blocks/CU;
// grid 1024 -> inter-block overlap preserved.
__launch_bounds__(256, 2)
__global__ void k1_qk(const _Float16* __restrict__ A, const _Float16* __restrict__ Bm,
                      _Float16* __restrict__ S, half2_t* __restrict__ pms) {
  __shared__ __align__(16) _Float16 lA[128 * 64];   // 16 KB
  __shared__ __align__(16) _Float16 lB[256 * 64];   // 32 KB
  int bid = blockIdx.x;
  int b = bid & 7;
  int t = bid >> 3;
  int tm = t & 15, tn = t >> 4;    // 16 m-tiles (128 rows), 8 n-tiles (256 cols)
  int tid = threadIdx.x;
  int w = tid >> 6, L = tid & 63;
  int wm = w & 1, wn = w >> 1;     // 2x2 wave grid; per-wave output 64 x 128
  int g = L >> 4, lm = L & 15;

  const _Float16* Ag = A + ((size_t)b * Ss + (size_t)tm * 128) * Dd;
  const _Float16* Bg = Bm + ((size_t)b * Ss + (size_t)tn * 256) * Dd;

  // Staging bases. Slot se(i) = base + i*512; row(i) = rz + i*8; octet col is
  // i-invariant: col = ((L&7) ^ (L>>3)) * 8  (row&7 == L>>3 for all i).
  int cswz = ((L & 7) ^ (L >> 3)) << 3;
  int rA0 = w * 32 + (L >> 3);               // A rows: + i*8, i<4  -> 0..127
  int rB0 = w * 64 + (L >> 3);               // B rows: + i*8, i<8  -> 0..255
  int slA = w * 2048 + L * 8;                // A slots: + i*512, i<4
  int slB = w * 4096 + L * 8;                // B slots: + i*512, i<8
  const _Float16* gA = Ag + (size_t)rA0 * Dd + cswz;
  const _Float16* gB = Bg + (size_t)rB0 * Dd + cswz;

  f32x4 acc[4][8];
#pragma unroll
  for (int mt = 0; mt < 4; ++mt)
#pragma unroll
    for (int nt = 0; nt < 8; ++nt) acc[mt][nt] = (f32x4){0.f, 0.f, 0.f, 0.f};

  for (int k0 = 0; k0 < Dd; k0 += 64) {
    __syncthreads();
#pragma unroll
    for (int i = 0; i < 4; ++i)
      gload_lds16(gA + (size_t)i * (8 * Dd) + k0, lA + slA + i * 512);
#pragma unroll
    for (int i = 0; i < 8; ++i)
      gload_lds16(gB + (size_t)i * (8 * Dd) + k0, lB + slB + i * 512);
    __syncthreads();
#pragma unroll
    for (int ds = 0; ds < 64; ds += 32) {
      half8 af[4];
#pragma unroll
      for (int mt = 0; mt < 4; ++mt) {
        int row = wm * 64 + mt * 16 + lm;
        int blk = ((ds >> 3) + g) ^ (row & 7);
        af[mt] = *(const half8*)(lA + row * 64 + blk * 8);
      }
#pragma unroll
      for (int nt = 0; nt < 8; ++nt) {
        int row = wn * 128 + nt * 16 + lm;
        int blk = ((ds >> 3) + g) ^ (row & 7);
        half8 bf = *(const half8*)(lB + row * 64 + blk * 8);
#pragma unroll
        for (int mt = 0; mt < 4; ++mt)
          acc[mt][nt] = __builtin_amdgcn_mfma_f32_16x16x32_f16(af[mt], bf, acc[mt][nt], 0, 0, 0);
      }
    }
  }

  // epilogue: per (row, 64-col chunk) max + exp + sum; wave covers 2 chunks (c2)
  size_t rowbase = (size_t)b * Ss;
#pragma unroll
  for (int mt = 0; mt < 4; ++mt) {
#pragma unroll
    for (int r = 0; r < 4; ++r) {
      int row_g = tm * 128 + wm * 64 + mt * 16 + g * 4 + r;
      _Float16* Srow = S + (rowbase + row_g) * Ss + (size_t)tn * 256 + wn * 128 + lm;
#pragma unroll
      for (int c2 = 0; c2 < 2; ++c2) {
        float rm = -1e30f;
#pragma unroll
        for (int q = 0; q < 4; ++q) rm = fmaxf(rm, acc[mt][c2 * 4 + q][r]);
        rm = fmaxf(rm, __shfl_xor(rm, 1));
        rm = fmaxf(rm, __shfl_xor(rm, 2));
        rm = fmaxf(rm, __shfl_xor(rm, 4));
        rm = fmaxf(rm, __shfl_xor(rm, 8));
        _Float16 mh = (_Float16)rm;   // f16-rounded chunk max; re-derived in k3 prologue
        float mf = (float)mh;
        float sum = 0.f;
#pragma unroll
        for (int q = 0; q < 4; ++q) {
          float e = __expf(acc[mt][c2 * 4 + q][r] - mf);
          Srow[(c2 * 4 + q) * 16] = (_Float16)e;
          sum += e;
        }
        sum += __shfl_xor(sum, 1);
        sum += __shfl_xor(sum, 2);
        sum += __shfl_xor(sum, 4);
        sum += __shfl_xor(sum, 8);
        if (lm == 0) {
          half2_t st; st.x = mh; st.y = (_Float16)sum;
          pms[(rowbase + row_g) * 32 + tn * 4 + wn * 2 + c2] = st;
        }
      }
    }
  }
}

// ---------------- K3: round-0 verified 128x64 tiles (reverted) ----------------
__launch_bounds__(256, 4)
__global__ void k3_pv(const _Float16* __restrict__ P, const _Float16* __restrict__ Vt,
                      const half2_t* __restrict__ pms, float* __restrict__ C) {
  __shared__ __align__(16) _Float16 lA[128 * 64];
  __shared__ __align__(16) _Float16 lB[64 * 64];
  __shared__ float fctL[32 * 128];  // [chunk][row] 16 KB
  int bid = blockIdx.x;
  int b = bid & 7;
  int t = bid >> 3;
  int tm = t & 15, tn = t >> 4;
  int tid = threadIdx.x;
  int w = tid >> 6, L = tid & 63;
  int wm = w & 1, wn = w >> 1;

  if (tid < 128) {
    const half2_t* pr = pms + ((size_t)b * Ss + (size_t)tm * 128 + tid) * 32;
    float mc[32], sc[32];
#pragma unroll
    for (int c = 0; c < 32; ++c) { half2_t v = pr[c]; mc[c] = (float)v.x; sc[c] = (float)v.y; }
    float m = mc[0];
#pragma unroll
    for (int c = 1; c < 32; ++c) m = fmaxf(m, mc[c]);
    float tot = 0.f;
    float ef[32];
#pragma unroll
    for (int c = 0; c < 32; ++c) { ef[c] = __expf(mc[c] - m); tot += sc[c] * ef[c]; }
    float rinv = 1.0f / tot;
#pragma unroll
    for (int c = 0; c < 32; ++c) fctL[c * 128 + tid] = ef[c] * rinv;
  }

  const _Float16* Ag = P + ((size_t)b * Ss + (size_t)tm * 128) * Ss;   // pitch 2048
  const _Float16* Bg = Vt + ((size_t)b * Dd + (size_t)tn * 64) * Ss;   // pitch 2048

  int rowA[4], colA[4], offA[4];
#pragma unroll
  for (int i = 0; i < 4; ++i) {
    int se = (w * 4 + i) * 512 + L * 8;
    int row = se >> 6;
    int blk = (se >> 3) & 7;
    rowA[i] = row;
    colA[i] = (blk ^ (row & 7)) << 3;
    offA[i] = se;
  }
  int rowB[2], colB[2], offB[2];
#pragma unroll
  for (int i = 0; i < 2; ++i) {
    int se = (w * 2 + i) * 512 + L * 8;
    int row = se >> 6;
    int blk = (se >> 3) & 7;
    rowB[i] = row;
    colB[i] = (blk ^ (row & 7)) << 3;
    offB[i] = se;
  }

  f32x4 acc[4][2];
#pragma unroll
  for (int mt = 0; mt < 4; ++mt)
#pragma unroll
    for (int nt = 0; nt < 2; ++nt) acc[mt][nt] = (f32x4){0.f, 0.f, 0.f, 0.f};

  int g = L >> 4, lm = L & 15;

  for (int k0 = 0; k0 < Ss; k0 += 64) {
    __syncthreads();
#pragma unroll
    for (int i = 0; i < 4; ++i)
      gload_lds16(Ag + (size_t)rowA[i] * Ss + k0 + colA[i], lA + offA[i]);
#pragma unroll
    for (int i = 0; i < 2; ++i)
      gload_lds16(Bg + (size_t)rowB[i] * Ss + k0 + colB[i], lB + offB[i]);
    __syncthreads();
    _Float16 fh[4];
#pragma unroll
    for (int mt = 0; mt < 4; ++mt)
      fh[mt] = (_Float16)fctL[(k0 >> 6) * 128 + wm * 64 + mt * 16 + lm];
#pragma unroll
    for (int ds = 0; ds < 64; ds += 32) {
      half8 af[4], bf[2];
#pragma unroll
      for (int mt = 0; mt < 4; ++mt) {
        int row = wm * 64 + mt * 16 + lm;
        int blk = ((ds >> 3) + g) ^ (row & 7);
        af[mt] = *(const half8*)(lA + row * 64 + blk * 8);
#pragma unroll
        for (int j = 0; j < 8; ++j) af[mt][j] *= fh[mt];
      }
#pragma unroll
      for (int nt = 0; nt < 2; ++nt) {
        int row = wn * 32 + nt * 16 + lm;
        int blk = ((ds >> 3) + g) ^ (row & 7);
        bf[nt] = *(const half8*)(lB + row * 64 + blk * 8);
      }
#pragma unroll
      for (int mt = 0; mt < 4; ++mt)
#pragma unroll
        for (int nt = 0; nt < 2; ++nt)
          acc[mt][nt] = __builtin_amdgcn_mfma_f32_16x16x32_f16(af[mt], bf[nt], acc[mt][nt], 0, 0, 0);
    }
  }

#pragma unroll
  for (int mt = 0; mt < 4; ++mt) {
#pragma unroll
    for (int r = 0; r < 4; ++r) {
      int row_g = tm * 128 + wm * 64 + mt * 16 + g * 4 + r;
      float* Crow = C + ((size_t)b * Ss + row_g) * Dd + (size_t)tn * 64 + wn * 32 + lm;
#pragma unroll
      for (int nt = 0; nt < 2; ++nt) Crow[nt * 16] = acc[mt][nt][r];
    }
  }
}

extern "C" void kernel_launch(void* const* d_in, const int* in_sizes, int n_in,
                              void* d_out, int out_size, void* d_ws, size_t ws_size,
                              hipStream_t stream) {
  const float* enc = (const float*)d_in[0];
  const float* dec = (const float*)d_in[1];
  float* out = (float*)d_out;

  const size_t nElem = (size_t)Bb * Ss * Dd;  // 8388608
  const size_t nS = (size_t)Bb * Ss * Ss;     // 33554432

  _Float16* dec16 = (_Float16*)d_ws;
  _Float16* enc16 = dec16 + nElem;
  _Float16* encT = enc16 + nElem;
  _Float16* Sp = encT + nElem;
  half2_t* pms = (half2_t*)(Sp + nS);

  size_t need = nElem * 2 * 3 + nS * 2 + (size_t)Bb * Ss * 32 * 4;
  if (ws_size < need) return;

  k0_prep<<<2048, 256, 0, stream>>>(enc, dec, enc16, encT, dec16);
  k1_qk<<<1024, 256, 0, stream>>>(dec16, enc16, Sp, pms);
  k3_pv<<<1024, 256, 0, stream>>>(Sp, encT, pms, out);
}